// Round 1
// baseline (237.972 us; speedup 1.0000x reference)
//
#include <hip/hip_runtime.h>
#include <math.h>

#define N_PTS   16384
#define F_DIM   64
#define K_BINS  32
#define C_DIM   128
#define FK      2048      // F*K
#define NB32    (N_PTS / 32)   // 512 n-blocks of 32
#define CW      132       // W row stride: [w0..w127, S1, B, pad0, pad0]
#define EPS_F   1e-8f
#define NCHUNK  16        // split-K chunks (was 32; halves wpart traffic)
#define CN      1024      // n per chunk (2 groups x 512)

typedef _Float16 f16x8 __attribute__((ext_vector_type(8)));
typedef float    f32x4 __attribute__((ext_vector_type(4)));

// ---------------------------------------------------------------------------
// K0: build Ybf — Y' transposed AND pre-blocked into MFMA B-fragment order.
//   Y'[n][c]: c 0..127 = teacher, 128 = y_sq, 129 = 1, 130..143 = 0.
//   Ybf[((ct*NB32 + nb)*64 + l)*8 + j] = Y'[nb*32 + (l>>4)*8 + j][ct*16 + (l&15)]
// Also zeroes the 8-float atomic accumulator block (4 sums + counter) that
// the fused epilogue uses — stream-ordered before epilogue_k, re-done every
// iteration so workspace poisoning is harmless.
// ---------------------------------------------------------------------------
__global__ __launch_bounds__(256) void build_ybf_k(const float* __restrict__ Y,
                                                   _Float16* __restrict__ Ybf,
                                                   float* __restrict__ accs) {
    __shared__ __align__(16) float Yl[64][132];
    __shared__ float ysql[64];
    const int t  = threadIdx.x;
    if (blockIdx.x == 0 && t < 8) accs[t] = 0.0f;   // zero sums + counter bits
    const int n0 = blockIdx.x * 64;
    const int nl = t >> 5;        // 0..7
    const int c4 = t & 31;
#pragma unroll
    for (int p = 0; p < 8; ++p) {
        const int n = p * 8 + nl;
        const float4 v = reinterpret_cast<const float4*>(Y + (size_t)(n0 + n) * C_DIM)[c4];
        reinterpret_cast<float4*>(Yl[n])[c4] = v;
        float sq = v.x * v.x + v.y * v.y + v.z * v.z + v.w * v.w;
#pragma unroll
        for (int m = 16; m >= 1; m >>= 1) sq += __shfl_xor(sq, m, 64);
        if (c4 == 0) ysql[n] = sq;
    }
    __syncthreads();
    // compose 1152 fragment-slots: (nb2, ct, l)
    for (int p = 0; p < 5; ++p) {
        const int s = t + p * 256;
        if (s < 1152) {
            const int nb2  = s / 576;
            const int r    = s % 576;
            const int ct   = r >> 6;
            const int l    = r & 63;
            const int quad = l >> 4, cl = l & 15;
            const int nloc = nb2 * 32 + quad * 8;
            f16x8 v;
            if (ct < 8) {
                const int c = ct * 16 + cl;
#pragma unroll
                for (int j = 0; j < 8; ++j) v[j] = (_Float16)Yl[nloc + j][c];
            } else if (cl == 0) {
#pragma unroll
                for (int j = 0; j < 8; ++j) v[j] = (_Float16)ysql[nloc + j];
            } else if (cl == 1) {
#pragma unroll
                for (int j = 0; j < 8; ++j) v[j] = (_Float16)1.0f;
            } else {
#pragma unroll
                for (int j = 0; j < 8; ++j) v[j] = (_Float16)0.0f;
            }
            const int nb = blockIdx.x * 2 + nb2;
            *reinterpret_cast<f16x8*>(Ybf + ((size_t)(ct * NB32 + nb) * 64 + l) * 8) = v;
        }
    }
}

// ---------------------------------------------------------------------------
// K1: split-K MFMA GEMM, nchunk=16.
// Block 256 thr = 4 waves = (2 fk-halves) x (2 n-groups). Each n-group runs
// the verified m97-style 2-barrier, double-buffered, 16-step pipeline over
// its own 512-n slice (so per-wave schedule is IDENTICAL to the previous
// 233us kernel); group 1's accumulators are merged in-block through LDS
// (aliasing the dead B buffers) so wpart holds 16 chunks, not 32.
// Grid 64x16 = 1024 blocks = 4/CU = 16 waves/CU — occupancy unchanged.
// fk-tile 32: a 64-B M line = 16 floats = one wave's cl range -> M read
// exactly once from HBM at full line utilization.
// ---------------------------------------------------------------------------
__global__ __launch_bounds__(256) void gemm_k(const float* __restrict__ M,
                                              const _Float16* __restrict__ Ybf,
                                              float* __restrict__ wpart) {
    __shared__ __align__(16) _Float16 Bb[2][2][9][512];   // [group][buf][ct][l*8] = 36,864 B
    const int t    = threadIdx.x;
    const int fk0  = blockIdx.x * 32;
    const int ch   = blockIdx.y;
    const int w    = t >> 6;       // 0..3
    const int g    = w >> 1;       // n-group (0/1)
    const int wl   = w & 1;        // fk-half within group
    const int l    = t & 63;
    const int quad = l >> 4;
    const int cl   = l & 15;
    const int fkA  = fk0 + wl * 16 + cl;
    const float* mp = M + fkA;
    const int n0   = ch * CN + g * 512;
    const int nb0  = n0 >> 5;

    f32x4 acc[9] = {};
    float a0r[8], a1r[8];

#define STAGE(s, par)                                                          \
    {                                                                          \
        const int nb_ = nb0 + (s);                                             \
        _Pragma("unroll")                                                      \
        for (int ct = wl; ct < 9; ct += 2) {                                   \
            const _Float16* g_ = Ybf + ((size_t)(ct * NB32 + nb_) * 64 + l) * 8; \
            __builtin_amdgcn_global_load_lds(                                  \
                (const __attribute__((address_space(1))) unsigned*)g_,         \
                (__attribute__((address_space(3))) unsigned*)&Bb[g][par][ct][0], \
                16, 0, 0);                                                     \
        }                                                                      \
    }
#define LOADA(ar, s)                                                           \
    {                                                                          \
        const size_t nbase_ = (size_t)(n0 + (s) * 32 + quad * 8);              \
        _Pragma("unroll")                                                      \
        for (int j = 0; j < 8; ++j) ar[j] = mp[(nbase_ + j) * FK];             \
    }

    STAGE(0, 0); LOADA(a0r, 0);
    STAGE(1, 1); LOADA(a1r, 1);

    for (int s = 0; s < 16; s += 2) {
        // ---- even step: buf 0 ----
        __syncthreads();                    // stage(s) landed in LDS
        {
            f16x8 bf[9];
#pragma unroll
            for (int ct = 0; ct < 9; ++ct)
                bf[ct] = *reinterpret_cast<const f16x8*>(&Bb[g][0][ct][l * 8]);
            f16x8 af;
#pragma unroll
            for (int j = 0; j < 8; ++j) af[j] = (_Float16)a0r[j];
            __syncthreads();                // all waves done reading buf0
            if (s + 2 < 16) { STAGE(s + 2, 0); LOADA(a0r, s + 2); }
#pragma unroll
            for (int ct = 0; ct < 9; ++ct)
                acc[ct] = __builtin_amdgcn_mfma_f32_16x16x32_f16(af, bf[ct], acc[ct], 0, 0, 0);
        }
        // ---- odd step: buf 1 ----
        __syncthreads();                    // stage(s+1) landed in LDS
        {
            f16x8 bf[9];
#pragma unroll
            for (int ct = 0; ct < 9; ++ct)
                bf[ct] = *reinterpret_cast<const f16x8*>(&Bb[g][1][ct][l * 8]);
            f16x8 af;
#pragma unroll
            for (int j = 0; j < 8; ++j) af[j] = (_Float16)a1r[j];
            __syncthreads();                // all waves done reading buf1
            if (s + 3 < 16) { STAGE(s + 3, 1); LOADA(a1r, s + 3); }
#pragma unroll
            for (int ct = 0; ct < 9; ++ct)
                acc[ct] = __builtin_amdgcn_mfma_f32_16x16x32_f16(af, bf[ct], acc[ct], 0, 0, 0);
        }
    }
#undef STAGE
#undef LOADA

    // ---- in-block merge of group 1 into group 0 (LDS scratch aliases Bb) ----
    // The last in-loop __syncthreads guarantees every wave finished its LDS
    // reads before any wave exits the loop, so Bb is dead and reusable.
    float* scr = reinterpret_cast<float*>(&Bb[0][0][0][0]);   // [32 rows][144 c] f32
    if (g == 1) {
#pragma unroll
        for (int ct = 0; ct < 9; ++ct)
#pragma unroll
            for (int r = 0; r < 4; ++r)
                scr[(wl * 16 + quad * 4 + r) * 144 + ct * 16 + cl] = acc[ct][r];
    }
    __syncthreads();
    if (g == 0) {
        // D layout: col(c) = lane&15, row(fk) = quad*4 + reg
        float* wp = wpart + (size_t)ch * FK * CW;
#pragma unroll
        for (int ct = 0; ct < 9; ++ct) {
            const int c = ct * 16 + cl;
            if (c < CW) {
#pragma unroll
                for (int r = 0; r < 4; ++r) {
                    const int row = wl * 16 + quad * 4 + r;
                    const int fk  = fk0 + row;
                    wp[(size_t)fk * CW + c] = acc[ct][r] + scr[row * 144 + c];
                }
            }
        }
    }
}

// ---------------------------------------------------------------------------
// R1: chunk reduction wpart -> W. 528 blocks x 128 thr, 4-way ILP over chunks.
// ---------------------------------------------------------------------------
__global__ __launch_bounds__(128) void reduce_w_k(const float* __restrict__ wpart,
                                                  float* __restrict__ W, int nchunk) {
    const int idx = blockIdx.x * 128 + threadIdx.x;   // float4 index, grid exact
    const float4* src = reinterpret_cast<const float4*>(wpart);
    const size_t cs = (size_t)FK * CW / 4;
    float4 s0 = make_float4(0.f, 0.f, 0.f, 0.f), s1 = s0, s2 = s0, s3 = s0;
    int ch = 0;
    for (; ch + 3 < nchunk; ch += 4) {
        const float4 a = src[idx + (size_t)(ch + 0) * cs];
        const float4 b = src[idx + (size_t)(ch + 1) * cs];
        const float4 c = src[idx + (size_t)(ch + 2) * cs];
        const float4 d = src[idx + (size_t)(ch + 3) * cs];
        s0.x += a.x; s0.y += a.y; s0.z += a.z; s0.w += a.w;
        s1.x += b.x; s1.y += b.y; s1.z += b.z; s1.w += b.w;
        s2.x += c.x; s2.y += c.y; s2.z += c.z; s2.w += c.w;
        s3.x += d.x; s3.y += d.y; s3.z += d.z; s3.w += d.w;
    }
    for (; ch < nchunk; ++ch) {
        const float4 a = src[idx + (size_t)ch * cs];
        s0.x += a.x; s0.y += a.y; s0.z += a.z; s0.w += a.w;
    }
    float4 r;
    r.x = (s0.x + s1.x) + (s2.x + s3.x);
    r.y = (s0.y + s1.y) + (s2.y + s3.y);
    r.z = (s0.z + s1.z) + (s2.z + s3.z);
    r.w = (s0.w + s1.w) + (s2.w + s3.w);
    reinterpret_cast<float4*>(W)[idx] = r;
}

// ---------------------------------------------------------------------------
// R2: per-feature epilogue on reduced W. wv = (S1 - c_sq*(B'+EPS))/B' (exact
// identity), entropy, neighbor repulsion, strict-upper Gram for inter.
// Final scalar reduction fused: device-scope atomics + last-block pattern
// (accs zeroed by build_ybf_k every iteration, stream-ordered).
// ---------------------------------------------------------------------------
__global__ __launch_bounds__(256) void epilogue_k(const float* __restrict__ W,
                                                  float* __restrict__ accs,
                                                  float* __restrict__ out) {
    __shared__ __align__(16) float Wl[32][CW];
    __shared__ float Bv[32], Binv[32], S1v[32], csq[32];
    __shared__ float scr[32][8];
    __shared__ float4 red4[256];
    const int t = threadIdx.x;
    const int f = blockIdx.x;

    for (int e = t; e < 32 * 33; e += 256) {
        const int k = e / 33, c4 = e % 33;
        reinterpret_cast<float4*>(Wl[k])[c4] =
            reinterpret_cast<const float4*>(W + (size_t)(f * 32 + k) * CW)[c4];
    }
    __syncthreads();
    if (t < 32) {
        const float B = Wl[t][129] + EPS_F;
        Bv[t] = B; Binv[t] = 1.0f / B; S1v[t] = Wl[t][128];
    }
    __syncthreads();
    {   // centroids in place + c_sq partials
        const int k = t >> 3, g = t & 7;
        const float ib = Binv[k];
        float s = 0.f;
        for (int c = g * 16; c < g * 16 + 16; ++c) {
            const float v = Wl[k][c] * ib;
            Wl[k][c] = v;
            s = fmaf(v, v, s);
        }
        scr[k][g] = s;
    }
    __syncthreads();
    if (t < 32) {
        float s = 0.f;
#pragma unroll
        for (int g = 0; g < 8; ++g) s += scr[t][g];
        csq[t] = s;
    }
    __syncthreads();

    float my_disp = 0.f, my_ent = 0.f, my_rep = 0.f, my_inter = 0.f;
    if (t < 32) {
        my_disp = (S1v[t] - csq[t] * (Bv[t] + EPS_F)) * Binv[t];
        const float p = Bv[t] * (1.0f / (float)N_PTS);
        my_ent = p * logf(p + EPS_F);
    }
    {   // neighbor repulsion
        const int pr = t >> 3, g = t & 7;
        float s = 0.f;
        if (pr < 31) {
            for (int c = g * 16; c < g * 16 + 16; ++c) {
                const float d = Wl[pr][c] - Wl[pr + 1][c];
                s = fmaf(d, d, s);
            }
        }
        __syncthreads();
        scr[pr][g] = s;
    }
    __syncthreads();
    if (t < 31) {
        float d = 0.f;
#pragma unroll
        for (int g = 0; g < 8; ++g) d += scr[t][g];
        my_rep = expf(-d);
    }
    // all-pairs inter (strict upper), float4 dots
#pragma unroll
    for (int s4 = 0; s4 < 4; ++s4) {
        const int slot = t + s4 * 256;
        const int k = slot >> 5, j = slot & 31;
        if (k < j) {
            float dot = 0.f;
            for (int c4 = 0; c4 < 32; ++c4) {
                const float4 a = reinterpret_cast<const float4*>(Wl[k])[c4];
                const float4 b = reinterpret_cast<const float4*>(Wl[j])[c4];
                dot = fmaf(a.x, b.x, dot); dot = fmaf(a.y, b.y, dot);
                dot = fmaf(a.z, b.z, dot); dot = fmaf(a.w, b.w, dot);
            }
            my_inter += expf(-(csq[k] + csq[j] - 2.0f * dot));
        }
    }
    red4[t] = make_float4(my_disp, my_ent, my_rep, my_inter);
    __syncthreads();
    for (int off = 128; off >= 1; off >>= 1) {
        if (t < off) {
            const float4 a = red4[t], b = red4[t + off];
            red4[t] = make_float4(a.x + b.x, a.y + b.y, a.z + b.z, a.w + b.w);
        }
        __syncthreads();
    }
    if (t == 0) {
        atomicAdd(accs + 0, red4[0].x);
        atomicAdd(accs + 1, red4[0].y);
        atomicAdd(accs + 2, red4[0].z);
        atomicAdd(accs + 3, red4[0].w);
        __threadfence();
        const unsigned prev = __hip_atomic_fetch_add(
            reinterpret_cast<unsigned*>(accs + 4), 1u,
            __ATOMIC_ACQ_REL, __HIP_MEMORY_SCOPE_AGENT);
        if (prev == (unsigned)(F_DIM - 1)) {
            const float disp = __hip_atomic_load(accs + 0, __ATOMIC_RELAXED, __HIP_MEMORY_SCOPE_AGENT);
            const float ent  = __hip_atomic_load(accs + 1, __ATOMIC_RELAXED, __HIP_MEMORY_SCOPE_AGENT);
            const float rep  = __hip_atomic_load(accs + 2, __ATOMIC_RELAXED, __HIP_MEMORY_SCOPE_AGENT);
            const float inter = __hip_atomic_load(accs + 3, __ATOMIC_RELAXED, __HIP_MEMORY_SCOPE_AGENT)
                                * (1.0f / (float)F_DIM);
            out[0] = disp + 0.1f * ent + 0.5f * rep + 0.3f * inter;
            out[1] = disp;
            out[2] = ent;
            out[3] = rep;
            out[4] = inter;
        }
    }
}

extern "C" void kernel_launch(void* const* d_in, const int* in_sizes, int n_in,
                              void* d_out, int out_size, void* d_ws, size_t ws_size,
                              hipStream_t stream) {
    const float* M = (const float*)d_in[0];   // (16384, 64, 32) fp32
    const float* Y = (const float*)d_in[1];   // (16384, 128) fp32
    float* out = (float*)d_out;               // 5 floats
    char*  ws  = (char*)d_ws;

    const size_t ybfBytes = (size_t)9 * NB32 * 64 * 8 * sizeof(_Float16);  // 4,718,592
    const size_t wBytes   = (size_t)FK * CW * sizeof(float);               // 1,081,344

    _Float16* Ybf   = (_Float16*)ws;
    float*    W     = (float*)(ws + ybfBytes);
    float*    accs  = (float*)(ws + ybfBytes + wBytes);        // 4 sums + counter
    float*    wpart = (float*)(ws + ybfBytes + wBytes + 1024);
    // total ws use: 4.72 + 1.08 + 16*1.08 MB ≈ 23.1 MB (was ~40.3 MB)

    build_ybf_k<<<dim3(N_PTS / 64), dim3(256), 0, stream>>>(Y, Ybf, accs);
    gemm_k<<<dim3(64, NCHUNK), dim3(256), 0, stream>>>(M, Ybf, wpart);
    reduce_w_k<<<dim3(FK * CW / 4 / 128), dim3(128), 0, stream>>>(wpart, W, NCHUNK);
    epilogue_k<<<dim3(F_DIM), dim3(256), 0, stream>>>(W, accs, out);
}

// Round 3
// 234.536 us; speedup vs baseline: 1.0147x; 1.0147x over previous
//
#include <hip/hip_runtime.h>
#include <math.h>

#define N_PTS   16384
#define F_DIM   64
#define K_BINS  32
#define C_DIM   128
#define FK      2048      // F*K
#define NB32    (N_PTS / 32)   // 512 n-blocks of 32
#define CW      132       // W row stride: [w0..w127, S1, B, pad0, pad0]
#define EPS_F   1e-8f
#define NCHUNK  16        // split-K chunks
#define CN      1024      // n per chunk (2 groups x 512)

typedef _Float16 f16x8 __attribute__((ext_vector_type(8)));
typedef float    f32x4 __attribute__((ext_vector_type(4)));

// ---------------------------------------------------------------------------
// K0: build Ybf — Y' transposed AND pre-blocked into MFMA B-fragment order.
//   Y'[n][c]: c 0..127 = teacher, 128 = y_sq, 129 = 1, 130..143 = 0.
//   Ybf[((ct*NB32 + nb)*64 + l)*8 + j] = Y'[nb*32 + (l>>4)*8 + j][ct*16 + (l&15)]
// Also zeroes the 8-float atomic accumulator block used by the fused epilogue
// (stream-ordered before epilogue_k; re-done every iteration so workspace
// poisoning is harmless).
// ---------------------------------------------------------------------------
__global__ __launch_bounds__(256) void build_ybf_k(const float* __restrict__ Y,
                                                   _Float16* __restrict__ Ybf,
                                                   float* __restrict__ accs) {
    __shared__ __align__(16) float Yl[64][132];
    __shared__ float ysql[64];
    const int t  = threadIdx.x;
    if (blockIdx.x == 0 && t < 8) accs[t] = 0.0f;   // zero sums + counter bits
    const int n0 = blockIdx.x * 64;
    const int nl = t >> 5;        // 0..7
    const int c4 = t & 31;
#pragma unroll
    for (int p = 0; p < 8; ++p) {
        const int n = p * 8 + nl;
        const float4 v = reinterpret_cast<const float4*>(Y + (size_t)(n0 + n) * C_DIM)[c4];
        reinterpret_cast<float4*>(Yl[n])[c4] = v;
        float sq = v.x * v.x + v.y * v.y + v.z * v.z + v.w * v.w;
#pragma unroll
        for (int m = 16; m >= 1; m >>= 1) sq += __shfl_xor(sq, m, 64);
        if (c4 == 0) ysql[n] = sq;
    }
    __syncthreads();
    // compose 1152 fragment-slots: (nb2, ct, l)
    for (int p = 0; p < 5; ++p) {
        const int s = t + p * 256;
        if (s < 1152) {
            const int nb2  = s / 576;
            const int r    = s % 576;
            const int ct   = r >> 6;
            const int l    = r & 63;
            const int quad = l >> 4, cl = l & 15;
            const int nloc = nb2 * 32 + quad * 8;
            f16x8 v;
            if (ct < 8) {
                const int c = ct * 16 + cl;
#pragma unroll
                for (int j = 0; j < 8; ++j) v[j] = (_Float16)Yl[nloc + j][c];
            } else if (cl == 0) {
#pragma unroll
                for (int j = 0; j < 8; ++j) v[j] = (_Float16)ysql[nloc + j];
            } else if (cl == 1) {
#pragma unroll
                for (int j = 0; j < 8; ++j) v[j] = (_Float16)1.0f;
            } else {
#pragma unroll
                for (int j = 0; j < 8; ++j) v[j] = (_Float16)0.0f;
            }
            const int nb = blockIdx.x * 2 + nb2;
            *reinterpret_cast<f16x8*>(Ybf + ((size_t)(ct * NB32 + nb) * 64 + l) * 8) = v;
        }
    }
}

// ---------------------------------------------------------------------------
// K1: split-K MFMA GEMM, nchunk=16, COUNTED-VMCNT schedule (T3+T4+T5).
// Round-1 rocprof: dur 79.6us, hbm 16%, MfmaUtil 4.5%, VALU 9.6% -> latency
// bound (__syncthreads drains vmcnt(0), killing the prefetch). Fix: raw
// s_barrier + exact counted vmcnt; A-prefetch 3 steps deep.
//
// VMEM issue order is PINNED with sched_barrier(0) fences so the per-wave
// queue at step-s entry is exactly (oldest->newest):
//   [la(s), st(s), la(s+1), st(s+1), la(s+2)]   (la=8 loads, st=S loads,
//                                                S=5 for wl=0, 4 for wl=1)
// Entry wait drains la(s)+st(s): remaining = la(s+1)+st(s+1)+la(s+2)
//   = S+16 -> use uniform vmcnt(20) (exact for S=4; one-load conservative
//   for S=5). Step 14: vmcnt(12). Step 15: vmcnt(0). Never a full drain
//   while work remains in flight.
// ---------------------------------------------------------------------------
__global__ __launch_bounds__(256) void gemm_k(const float* __restrict__ M,
                                              const _Float16* __restrict__ Ybf,
                                              float* __restrict__ wpart) {
    __shared__ __align__(16) _Float16 Bb[2][2][9][512];   // [group][buf][ct][l*8] = 36,864 B
    const int t    = threadIdx.x;
    const int fk0  = blockIdx.x * 32;
    const int ch   = blockIdx.y;
    const int w    = t >> 6;       // 0..3
    const int g    = w >> 1;       // n-group (0/1)
    const int wl   = w & 1;        // fk-half within group
    const int l    = t & 63;
    const int quad = l >> 4;
    const int cl   = l & 15;
    const int fkA  = fk0 + wl * 16 + cl;
    const float* mp = M + fkA;
    const int n0   = ch * CN + g * 512;
    const int nb0  = n0 >> 5;

    f32x4 acc[9] = {};
    float ar[3][8];

#define WAITVM(n) asm volatile("s_waitcnt vmcnt(" #n ")" ::: "memory")
#define STAGE(s, par)                                                          \
    {                                                                          \
        const int nb_ = nb0 + (s);                                             \
        _Pragma("unroll")                                                      \
        for (int ct = wl; ct < 9; ct += 2) {                                   \
            const _Float16* g_ = Ybf + ((size_t)(ct * NB32 + nb_) * 64 + l) * 8; \
            __builtin_amdgcn_global_load_lds(                                  \
                (const __attribute__((address_space(1))) unsigned*)g_,         \
                (__attribute__((address_space(3))) unsigned*)&Bb[g][par][ct][0], \
                16, 0, 0);                                                     \
        }                                                                      \
    }
#define LOADA(s)                                                               \
    {                                                                          \
        const size_t nbase_ = (size_t)(n0 + (s) * 32 + quad * 8);              \
        _Pragma("unroll")                                                      \
        for (int j = 0; j < 8; ++j) ar[(s) % 3][j] = mp[(nbase_ + j) * FK];    \
    }
#define SBAR0() __builtin_amdgcn_sched_barrier(0)

    // prologue, issue order pinned: st0, la0, st1, la1, la2
    STAGE(0, 0); SBAR0(); LOADA(0); SBAR0();
    STAGE(1, 1); SBAR0(); LOADA(1); SBAR0(); LOADA(2); SBAR0();

#pragma unroll
    for (int s = 0; s < 16; ++s) {
        // entry wait: stage(s) + loada(s) complete; next batches stay in flight
        if (s < 14)       WAITVM(20);
        else if (s == 14) WAITVM(12);
        else              WAITVM(0);
        __builtin_amdgcn_s_barrier();            // B1: all waves' stage(s) landed
        SBAR0();                                 // no ds_read hoists above B1
        f16x8 bf[9];
#pragma unroll
        for (int ct = 0; ct < 9; ++ct)
            bf[ct] = *reinterpret_cast<const f16x8*>(&Bb[g][s & 1][ct][l * 8]);
        f16x8 af;
#pragma unroll
        for (int j = 0; j < 8; ++j) af[j] = (_Float16)ar[s % 3][j];
        asm volatile("s_waitcnt lgkmcnt(0)" ::: "memory");  // my LDS reads done
        SBAR0();
        __builtin_amdgcn_s_barrier();            // B2: everyone's reads done
        SBAR0();                                 // no STAGE hoists above B2
        if (s + 2 < 16) STAGE(s + 2, s & 1);
        SBAR0();                                 // pin: STAGE before LOADA
        if (s + 3 < 16) LOADA(s + 3);
        SBAR0();                                 // pin: loads issued before MFMA
        __builtin_amdgcn_s_setprio(1);
#pragma unroll
        for (int ct = 0; ct < 9; ++ct)
            acc[ct] = __builtin_amdgcn_mfma_f32_16x16x32_f16(af, bf[ct], acc[ct], 0, 0, 0);
        __builtin_amdgcn_s_setprio(0);
    }
#undef WAITVM
#undef STAGE
#undef LOADA
#undef SBAR0

    // ---- in-block merge of group 1 into group 0 (LDS scratch aliases Bb) ----
    // Step-15 entry drained vmcnt(0); every wave's ds_reads completed before
    // its final B2; __syncthreads fences the ds_write->ds_read handoff.
    __syncthreads();
    float* scr = reinterpret_cast<float*>(&Bb[0][0][0][0]);   // [32 rows][144 c] f32
    if (g == 1) {
#pragma unroll
        for (int ct = 0; ct < 9; ++ct)
#pragma unroll
            for (int r = 0; r < 4; ++r)
                scr[(wl * 16 + quad * 4 + r) * 144 + ct * 16 + cl] = acc[ct][r];
    }
    __syncthreads();
    if (g == 0) {
        // D layout: col(c) = lane&15, row(fk) = quad*4 + reg
        float* wp = wpart + (size_t)ch * FK * CW;
#pragma unroll
        for (int ct = 0; ct < 9; ++ct) {
            const int c = ct * 16 + cl;
            if (c < CW) {
#pragma unroll
                for (int r = 0; r < 4; ++r) {
                    const int row = wl * 16 + quad * 4 + r;
                    const int fk  = fk0 + row;
                    wp[(size_t)fk * CW + c] = acc[ct][r] + scr[row * 144 + c];
                }
            }
        }
    }
}

// ---------------------------------------------------------------------------
// R1: chunk reduction wpart -> W. 528 blocks x 128 thr, 4-way ILP over chunks.
// ---------------------------------------------------------------------------
__global__ __launch_bounds__(128) void reduce_w_k(const float* __restrict__ wpart,
                                                  float* __restrict__ W, int nchunk) {
    const int idx = blockIdx.x * 128 + threadIdx.x;   // float4 index, grid exact
    const float4* src = reinterpret_cast<const float4*>(wpart);
    const size_t cs = (size_t)FK * CW / 4;
    float4 s0 = make_float4(0.f, 0.f, 0.f, 0.f), s1 = s0, s2 = s0, s3 = s0;
    int ch = 0;
    for (; ch + 3 < nchunk; ch += 4) {
        const float4 a = src[idx + (size_t)(ch + 0) * cs];
        const float4 b = src[idx + (size_t)(ch + 1) * cs];
        const float4 c = src[idx + (size_t)(ch + 2) * cs];
        const float4 d = src[idx + (size_t)(ch + 3) * cs];
        s0.x += a.x; s0.y += a.y; s0.z += a.z; s0.w += a.w;
        s1.x += b.x; s1.y += b.y; s1.z += b.z; s1.w += b.w;
        s2.x += c.x; s2.y += c.y; s2.z += c.z; s2.w += c.w;
        s3.x += d.x; s3.y += d.y; s3.z += d.z; s3.w += d.w;
    }
    for (; ch < nchunk; ++ch) {
        const float4 a = src[idx + (size_t)ch * cs];
        s0.x += a.x; s0.y += a.y; s0.z += a.z; s0.w += a.w;
    }
    float4 r;
    r.x = (s0.x + s1.x) + (s2.x + s3.x);
    r.y = (s0.y + s1.y) + (s2.y + s3.y);
    r.z = (s0.z + s1.z) + (s2.z + s3.z);
    r.w = (s0.w + s1.w) + (s2.w + s3.w);
    reinterpret_cast<float4*>(W)[idx] = r;
}

// ---------------------------------------------------------------------------
// R2: per-feature epilogue on reduced W. wv = (S1 - c_sq*(B'+EPS))/B' (exact
// identity), entropy, neighbor repulsion, strict-upper Gram for inter.
// Final scalar reduction fused: device-scope atomics + last-block pattern
// (accs zeroed by build_ybf_k every iteration, stream-ordered).
// ---------------------------------------------------------------------------
__global__ __launch_bounds__(256) void epilogue_k(const float* __restrict__ W,
                                                  float* __restrict__ accs,
                                                  float* __restrict__ out) {
    __shared__ __align__(16) float Wl[32][CW];
    __shared__ float Bv[32], Binv[32], S1v[32], csq[32];
    __shared__ float scr[32][8];
    __shared__ float4 red4[256];
    const int t = threadIdx.x;
    const int f = blockIdx.x;

    for (int e = t; e < 32 * 33; e += 256) {
        const int k = e / 33, c4 = e % 33;
        reinterpret_cast<float4*>(Wl[k])[c4] =
            reinterpret_cast<const float4*>(W + (size_t)(f * 32 + k) * CW)[c4];
    }
    __syncthreads();
    if (t < 32) {
        const float B = Wl[t][129] + EPS_F;
        Bv[t] = B; Binv[t] = 1.0f / B; S1v[t] = Wl[t][128];
    }
    __syncthreads();
    {   // centroids in place + c_sq partials
        const int k = t >> 3, g = t & 7;
        const float ib = Binv[k];
        float s = 0.f;
        for (int c = g * 16; c < g * 16 + 16; ++c) {
            const float v = Wl[k][c] * ib;
            Wl[k][c] = v;
            s = fmaf(v, v, s);
        }
        scr[k][g] = s;
    }
    __syncthreads();
    if (t < 32) {
        float s = 0.f;
#pragma unroll
        for (int g = 0; g < 8; ++g) s += scr[t][g];
        csq[t] = s;
    }
    __syncthreads();

    float my_disp = 0.f, my_ent = 0.f, my_rep = 0.f, my_inter = 0.f;
    if (t < 32) {
        my_disp = (S1v[t] - csq[t] * (Bv[t] + EPS_F)) * Binv[t];
        const float p = Bv[t] * (1.0f / (float)N_PTS);
        my_ent = p * logf(p + EPS_F);
    }
    {   // neighbor repulsion
        const int pr = t >> 3, g = t & 7;
        float s = 0.f;
        if (pr < 31) {
            for (int c = g * 16; c < g * 16 + 16; ++c) {
                const float d = Wl[pr][c] - Wl[pr + 1][c];
                s = fmaf(d, d, s);
            }
        }
        __syncthreads();
        scr[pr][g] = s;
    }
    __syncthreads();
    if (t < 31) {
        float d = 0.f;
#pragma unroll
        for (int g = 0; g < 8; ++g) d += scr[t][g];
        my_rep = expf(-d);
    }
    // all-pairs inter (strict upper), float4 dots
#pragma unroll
    for (int s4 = 0; s4 < 4; ++s4) {
        const int slot = t + s4 * 256;
        const int k = slot >> 5, j = slot & 31;
        if (k < j) {
            float dot = 0.f;
            for (int c4 = 0; c4 < 32; ++c4) {
                const float4 a = reinterpret_cast<const float4*>(Wl[k])[c4];
                const float4 b = reinterpret_cast<const float4*>(Wl[j])[c4];
                dot = fmaf(a.x, b.x, dot); dot = fmaf(a.y, b.y, dot);
                dot = fmaf(a.z, b.z, dot); dot = fmaf(a.w, b.w, dot);
            }
            my_inter += expf(-(csq[k] + csq[j] - 2.0f * dot));
        }
    }
    red4[t] = make_float4(my_disp, my_ent, my_rep, my_inter);
    __syncthreads();
    for (int off = 128; off >= 1; off >>= 1) {
        if (t < off) {
            const float4 a = red4[t], b = red4[t + off];
            red4[t] = make_float4(a.x + b.x, a.y + b.y, a.z + b.z, a.w + b.w);
        }
        __syncthreads();
    }
    if (t == 0) {
        atomicAdd(accs + 0, red4[0].x);
        atomicAdd(accs + 1, red4[0].y);
        atomicAdd(accs + 2, red4[0].z);
        atomicAdd(accs + 3, red4[0].w);
        __threadfence();
        const unsigned prev = __hip_atomic_fetch_add(
            reinterpret_cast<unsigned*>(accs + 4), 1u,
            __ATOMIC_ACQ_REL, __HIP_MEMORY_SCOPE_AGENT);
        if (prev == (unsigned)(F_DIM - 1)) {
            const float disp = __hip_atomic_load(accs + 0, __ATOMIC_RELAXED, __HIP_MEMORY_SCOPE_AGENT);
            const float ent  = __hip_atomic_load(accs + 1, __ATOMIC_RELAXED, __HIP_MEMORY_SCOPE_AGENT);
            const float rep  = __hip_atomic_load(accs + 2, __ATOMIC_RELAXED, __HIP_MEMORY_SCOPE_AGENT);
            const float inter = __hip_atomic_load(accs + 3, __ATOMIC_RELAXED, __HIP_MEMORY_SCOPE_AGENT)
                                * (1.0f / (float)F_DIM);
            out[0] = disp + 0.1f * ent + 0.5f * rep + 0.3f * inter;
            out[1] = disp;
            out[2] = ent;
            out[3] = rep;
            out[4] = inter;
        }
    }
}

extern "C" void kernel_launch(void* const* d_in, const int* in_sizes, int n_in,
                              void* d_out, int out_size, void* d_ws, size_t ws_size,
                              hipStream_t stream) {
    const float* M = (const float*)d_in[0];   // (16384, 64, 32) fp32
    const float* Y = (const float*)d_in[1];   // (16384, 128) fp32
    float* out = (float*)d_out;               // 5 floats
    char*  ws  = (char*)d_ws;

    const size_t ybfBytes = (size_t)9 * NB32 * 64 * 8 * sizeof(_Float16);  // 4,718,592
    const size_t wBytes   = (size_t)FK * CW * sizeof(float);               // 1,081,344

    _Float16* Ybf   = (_Float16*)ws;
    float*    W     = (float*)(ws + ybfBytes);
    float*    accs  = (float*)(ws + ybfBytes + wBytes);        // 4 sums + counter
    float*    wpart = (float*)(ws + ybfBytes + wBytes + 1024);

    build_ybf_k<<<dim3(N_PTS / 64), dim3(256), 0, stream>>>(Y, Ybf, accs);
    gemm_k<<<dim3(64, NCHUNK), dim3(256), 0, stream>>>(M, Ybf, wpart);
    reduce_w_k<<<dim3(FK * CW / 4 / 128), dim3(128), 0, stream>>>(wpart, W, NCHUNK);
    epilogue_k<<<dim3(F_DIM), dim3(256), 0, stream>>>(W, accs, out);
}